// Round 1
// baseline (327.621 us; speedup 1.0000x reference)
//
#include <hip/hip_runtime.h>

#define GXv 512
#define GYv 512
#define PMAX 32

constexpr int SCAN_TPB = 256;
constexpr int EPT = 8;                  // elements per thread in scan kernels
constexpr int EPB = SCAN_TPB * EPT;     // 2048 elements per block

// ---- zero an int4 region ----
__global__ void zero_int4_kernel(int4* __restrict__ p, int n4) {
    int i = blockIdx.x * blockDim.x + threadIdx.x;
    if (i < n4) p[i] = make_int4(0, 0, 0, 0);
}

// ---- per-point: counts + last-write-wins position ----
__global__ void points_kernel(const float4* __restrict__ pts, const int* __restrict__ bidx,
                              int* __restrict__ counts, int* __restrict__ lastp, int N) {
    int i = blockIdx.x * blockDim.x + threadIdx.x;
    if (i >= N) return;
    float4 p = pts[i];
    // EXACT f32 division to match the numpy reference (do NOT use * 5.0f)
    int x = (int)(p.x / 0.2f);
    int y = (int)(p.y / 0.2f);
    x = min(max(x, 0), GXv - 1);
    y = min(max(y, 0), GYv - 1);
    int flat = bidx[i] * (GXv * GYv) + x * GYv + y;
    atomicAdd(&counts[flat], 1);
    atomicMax(&lastp[flat], i + 1);   // store pos+1 so 0 == empty
}

// ---- per-block sum of occupied flags ----
__global__ void blocksum_kernel(const int* __restrict__ counts, int* __restrict__ blockSums, int G) {
    int t = threadIdx.x;
    int base = blockIdx.x * EPB + t * EPT;
    int s = 0;
#pragma unroll
    for (int k = 0; k < EPT; k++) {
        int g = base + k;
        if (g < G) s += (counts[g] > 0) ? 1 : 0;
    }
    __shared__ int sm[SCAN_TPB];
    sm[t] = s;
    __syncthreads();
    for (int off = SCAN_TPB / 2; off > 0; off >>= 1) {
        if (t < off) sm[t] += sm[t + off];
        __syncthreads();
    }
    if (t == 0) blockSums[blockIdx.x] = sm[0];
}

// ---- single-block exclusive scan of block sums (nb <= 1024) ----
__global__ void scan_kernel(int* __restrict__ blockSums, int nb) {
    __shared__ int sm[1024];
    int t = threadIdx.x;
    int v = (t < nb) ? blockSums[t] : 0;
    sm[t] = v;
    __syncthreads();
    for (int off = 1; off < 1024; off <<= 1) {
        int add = (t >= off) ? sm[t - off] : 0;
        __syncthreads();
        sm[t] += add;
        __syncthreads();
    }
    if (t < nb) blockSums[t] = (t == 0) ? 0 : sm[t - 1];
}

// ---- recompute ranks per block, scatter winner points into compact[rank] ----
__global__ void scatter_kernel(const int* __restrict__ counts, const int* __restrict__ lastp,
                               const int* __restrict__ blockOffsets, const float4* __restrict__ pts,
                               float4* __restrict__ compact, int G) {
    int t = threadIdx.x;
    int base = blockIdx.x * EPB + t * EPT;
    int cnt[EPT];
    int s = 0;
#pragma unroll
    for (int k = 0; k < EPT; k++) {
        int g = base + k;
        cnt[k] = (g < G) ? counts[g] : 0;
        s += (cnt[k] > 0) ? 1 : 0;
    }
    __shared__ int sm[SCAN_TPB];
    sm[t] = s;
    __syncthreads();
    for (int off = 1; off < SCAN_TPB; off <<= 1) {
        int add = (t >= off) ? sm[t - off] : 0;
        __syncthreads();
        sm[t] += add;
        __syncthreads();
    }
    int rank = blockOffsets[blockIdx.x] + ((t == 0) ? 0 : sm[t - 1]);
#pragma unroll
    for (int k = 0; k < EPT; k++) {
        int g = base + k;
        if (g < G && cnt[k] > 0) {
            if (cnt[k] <= PMAX) {
                int p = lastp[g] - 1;      // last point index in this pillar
                compact[rank] = pts[p];
            }
            // over-full pillar: compact[rank] stays zero (pre-zeroed) == reference
            rank++;
        }
    }
}

// ---- broadcast compact[j] over the P=32 slot dimension ----
__global__ void broadcast_kernel(const float4* __restrict__ compact, float4* __restrict__ out4, int total4) {
    int i = blockIdx.x * blockDim.x + threadIdx.x;
    if (i < total4) out4[i] = compact[i >> 5];
}

extern "C" void kernel_launch(void* const* d_in, const int* in_sizes, int n_in,
                              void* d_out, int out_size, void* d_ws, size_t ws_size,
                              hipStream_t stream) {
    const float4* pts = (const float4*)d_in[0];
    const int* bidx = (const int*)d_in[1];
    int N = in_sizes[0] / 4;
    // out = features (G*P*C floats) ++ counts (G ints)  => out_size = G*129
    int G = out_size / 129;

    // ws layout: counts[G] | lastp[G] | compact[G]{float4} | blockSums[nb]
    int* counts = (int*)d_ws;
    int* lastp = counts + G;
    float4* compact = (float4*)(lastp + G);
    int* blockSums = (int*)(compact + G);
    int nb = (G + EPB - 1) / EPB;

    // zero counts + lastp + compact = 6G ints = (6G/4) int4
    int nz4 = (6 * G) / 4;
    zero_int4_kernel<<<(nz4 + 255) / 256, 256, 0, stream>>>((int4*)d_ws, nz4);

    points_kernel<<<(N + 255) / 256, 256, 0, stream>>>(pts, bidx, counts, lastp, N);
    blocksum_kernel<<<nb, SCAN_TPB, 0, stream>>>(counts, blockSums, G);
    scan_kernel<<<1, 1024, 0, stream>>>(blockSums, nb);
    scatter_kernel<<<nb, SCAN_TPB, 0, stream>>>(counts, lastp, blockSums, pts, compact, G);

    int total4 = G * PMAX;  // one float4 per (slot, p)
    broadcast_kernel<<<(total4 + 255) / 256, 256, 0, stream>>>(compact, (float4*)d_out, total4);

    // voxel_counts output: G int32 zeros right after the features
    int nc4 = G / 4;
    zero_int4_kernel<<<(nc4 + 255) / 256, 256, 0, stream>>>(
        (int4*)((float*)d_out + (long)G * (PMAX * 4)), nc4);
}